// Round 8
// baseline (444.363 us; speedup 1.0000x reference)
//
#include <hip/hip_runtime.h>
#include <hip/hip_bf16.h>

// Problem constants: V=128000, D=512, B=2, T=1024, K=512
#define V_SZ   128000
#define D_SZ   512
#define N_ROWS 2048
#define K_SZ   512
#define KM1    511
#define W_ELEMS   ((size_t)V_SZ * D_SZ)     // 65,536,000

typedef float v2f __attribute__((ext_vector_type(2)));

#if defined(__has_builtin)
#if __has_builtin(__builtin_amdgcn_cvt_pk_f32_fp8) && __has_builtin(__builtin_amdgcn_cvt_pk_fp8_f32)
#define HW_FP8 1
#endif
#if __has_builtin(__builtin_amdgcn_perm)
#define HAVE_PERM 1
#endif
#endif

// ---------- fp8 e4m3 decode/encode (HW path; manual bit-trick fallback) ----------
#ifdef HW_FP8
__device__ __forceinline__ unsigned pack4(float a, float b, float c, float d) {
    int u = 0;
    u = __builtin_amdgcn_cvt_pk_fp8_f32(a, b, u, false);
    u = __builtin_amdgcn_cvt_pk_fp8_f32(c, d, u, true);
    return (unsigned)u;
}
#define F8X2(u, hi) __builtin_amdgcn_cvt_pk_f32_fp8((int)(u), (hi))
#else
__device__ __forceinline__ unsigned enc1(float f) {
    unsigned b = __float_as_uint(f);
    unsigned sgn = (b >> 24) & 0x80u;
    unsigned mag = (b & 0x7fffffffu) + 0x00080000u;
    int e = (int)(mag >> 23) - 120;
    unsigned m = (mag >> 20) & 7u;
    unsigned val = (e <= 0) ? 0u : ((e >= 16) ? 0x7eu : (((unsigned)e << 3) | m));
    return sgn | val;
}
__device__ __forceinline__ unsigned pack4(float a, float b, float c, float d) {
    return enc1(a) | (enc1(b) << 8) | (enc1(c) << 16) | (enc1(d) << 24);
}
__device__ __forceinline__ v2f f8x2m(unsigned u, int hi) {
    unsigned b0 = (u >> (hi ? 16 : 0)) & 0xffu;
    unsigned b1 = (u >> (hi ? 24 : 8)) & 0xffu;
    unsigned u0 = ((b0 & 0x7fu) << 20) + (120u << 23); u0 |= (b0 & 0x80u) << 24;
    unsigned u1 = ((b1 & 0x7fu) << 20) + (120u << 23); u1 |= (b1 & 0x80u) << 24;
    v2f r; r.x = __uint_as_float(u0); r.y = __uint_as_float(u1);
    return r;
}
#define F8X2(u, hi) f8x2m((u), (hi))
#endif

// ======================= FP4 path =======================
#ifdef HAVE_PERM
#define SCALE4     48.0f
#define INV_SCALE4 (1.0f / 48.0f)
// e2m1 magnitude code -> e4m3 byte LUT (codes 0..7 -> {0,.5,1,1.5,2,3,4,6})
#define POOL_LO 0x3C383000u   // bytes: 0x00,0x30,0x38,0x3C  (codes 0-3)
#define POOL_HI 0x4C484440u   // bytes: 0x40,0x44,0x48,0x4C  (codes 4-7)

// round-to-nearest e2m1 code of |v| clamped to 6, plus sign in bit 3
__device__ __forceinline__ unsigned enc_fp4(float v) {
    float a = fminf(fabsf(v), 6.0f);
    unsigned c;
    if (a < 2.25f) c = (unsigned)(int)rintf(a + a);                 // codes 0..4
    else c = (a < 2.5f) ? 4u : (a < 3.5f) ? 5u : (a < 5.0f) ? 6u : 7u;
    return c | ((__float_as_uint(v) >> 28) & 8u);
}

// dot of 8 fp4 (one u32; nibble p = element p) with h[0..7]
__device__ __forceinline__ float dot8_fp4(unsigned u, const float* h, float s) {
    unsigned lo  = u & 0x07070707u;            // mag codes of elems 0,2,4,6
    unsigned hi  = (u >> 4) & 0x07070707u;     // mag codes of elems 1,3,5,7
    unsigned slo = (u & 0x08080808u) << 4;     // signs -> byte bit7
    unsigned shi = ((u >> 4) & 0x08080808u) << 4;
    unsigned f8a = __builtin_amdgcn_perm(POOL_HI, POOL_LO, lo) | slo;
    unsigned f8b = __builtin_amdgcn_perm(POOL_HI, POOL_LO, hi) | shi;
    v2f p;
    p = F8X2(f8a, 0); s = fmaf(p.x, h[0], s); s = fmaf(p.y, h[2], s);
    p = F8X2(f8a, 1); s = fmaf(p.x, h[4], s); s = fmaf(p.y, h[6], s);
    p = F8X2(f8b, 0); s = fmaf(p.x, h[1], s); s = fmaf(p.y, h[3], s);
    p = F8X2(f8b, 1); s = fmaf(p.x, h[5], s); s = fmaf(p.y, h[7], s);
    return s;
}

// ---------- W fp32 -> fp4 (scaled by 48) into d_ws; also zeroes out[0] ----------
__global__ __launch_bounds__(256) void k_convert_fp4(const float* __restrict__ W,
                                                     unsigned* __restrict__ W4,
                                                     float* __restrict__ out) {
    if (blockIdx.x == 0 && threadIdx.x == 0) out[0] = 0.0f;
    const size_t nvec = W_ELEMS / 8;                 // one u32 out per 8 elems
    const size_t stride = (size_t)gridDim.x * 256;
    for (size_t i = (size_t)blockIdx.x * 256 + threadIdx.x; i < nvec; i += stride) {
        float4 v0 = reinterpret_cast<const float4*>(W)[2 * i];
        float4 v1 = reinterpret_cast<const float4*>(W)[2 * i + 1];
        unsigned u = enc_fp4(v0.x * SCALE4)
                   | (enc_fp4(v0.y * SCALE4) << 4)
                   | (enc_fp4(v0.z * SCALE4) << 8)
                   | (enc_fp4(v0.w * SCALE4) << 12)
                   | (enc_fp4(v1.x * SCALE4) << 16)
                   | (enc_fp4(v1.y * SCALE4) << 20)
                   | (enc_fp4(v1.z * SCALE4) << 24)
                   | (enc_fp4(v1.w * SCALE4) << 28);
        W4[i] = u;
    }
}

// ---------- monolithic sampled-softmax with fp4 W gather ----------
__global__ __launch_bounds__(256) void k_main_fp4(
    const float* __restrict__ H, const int* __restrict__ labels,
    const unsigned* __restrict__ W4, const float* __restrict__ q,
    const int* __restrict__ neg, float* __restrict__ out)
{
    const int n   = blockIdx.x;
    const int tid = threadIdx.x;
    const int sub = tid & 15;   // lane in 16-lane candidate group
    const int grp = tid >> 4;

    __shared__ int   cidx[K_SZ];
    __shared__ float logits[K_SZ];
    __shared__ float red[4];

    for (int i = tid; i < K_SZ; i += 256)
        cidx[i] = (i == 0) ? labels[n] : neg[(size_t)n * KM1 + (i - 1)];

    // lane sub covers elements [sub*32, sub*32+32): 8 float4s, kept scalar
    float h[32];
    const float4* Hr4 = reinterpret_cast<const float4*>(H + (size_t)n * D_SZ);
    #pragma unroll
    for (int j = 0; j < 8; ++j) {
        float4 t = Hr4[sub * 8 + j];
        h[4 * j] = t.x; h[4 * j + 1] = t.y; h[4 * j + 2] = t.z; h[4 * j + 3] = t.w;
    }
    __syncthreads();

    // 4 candidates per iteration -> 4 independent 16B loads in flight
    for (int base = grp; base < K_SZ; base += 64) {
        const int c0 = cidx[base], c1 = cidx[base + 16];
        const int c2 = cidx[base + 32], c3 = cidx[base + 48];
        const uint4* p0 = reinterpret_cast<const uint4*>(W4 + (size_t)c0 * (D_SZ / 8));
        const uint4* p1 = reinterpret_cast<const uint4*>(W4 + (size_t)c1 * (D_SZ / 8));
        const uint4* p2 = reinterpret_cast<const uint4*>(W4 + (size_t)c2 * (D_SZ / 8));
        const uint4* p3 = reinterpret_cast<const uint4*>(W4 + (size_t)c3 * (D_SZ / 8));
        uint4 a = p0[sub], b = p1[sub], c = p2[sub], d = p3[sub];  // 256B/candidate
        float s0 = 0.f, s1 = 0.f, s2 = 0.f, s3 = 0.f;
        s0 = dot8_fp4(a.x, h,      s0); s0 = dot8_fp4(a.y, h + 8,  s0);
        s0 = dot8_fp4(a.z, h + 16, s0); s0 = dot8_fp4(a.w, h + 24, s0);
        s1 = dot8_fp4(b.x, h,      s1); s1 = dot8_fp4(b.y, h + 8,  s1);
        s1 = dot8_fp4(b.z, h + 16, s1); s1 = dot8_fp4(b.w, h + 24, s1);
        s2 = dot8_fp4(c.x, h,      s2); s2 = dot8_fp4(c.y, h + 8,  s2);
        s2 = dot8_fp4(c.z, h + 16, s2); s2 = dot8_fp4(c.w, h + 24, s2);
        s3 = dot8_fp4(d.x, h,      s3); s3 = dot8_fp4(d.y, h + 8,  s3);
        s3 = dot8_fp4(d.z, h + 16, s3); s3 = dot8_fp4(d.w, h + 24, s3);
        s0 += __shfl_xor(s0, 1); s1 += __shfl_xor(s1, 1);
        s2 += __shfl_xor(s2, 1); s3 += __shfl_xor(s3, 1);
        s0 += __shfl_xor(s0, 2); s1 += __shfl_xor(s1, 2);
        s2 += __shfl_xor(s2, 2); s3 += __shfl_xor(s3, 2);
        s0 += __shfl_xor(s0, 4); s1 += __shfl_xor(s1, 4);
        s2 += __shfl_xor(s2, 4); s3 += __shfl_xor(s3, 4);
        s0 += __shfl_xor(s0, 8); s1 += __shfl_xor(s1, 8);
        s2 += __shfl_xor(s2, 8); s3 += __shfl_xor(s3, 8);
        if (sub == 0) {
            logits[base]      = s0 * INV_SCALE4;
            logits[base + 16] = s1 * INV_SCALE4;
            logits[base + 32] = s2 * INV_SCALE4;
            logits[base + 48] = s3 * INV_SCALE4;
        }
    }
    __syncthreads();

    const int wave = tid >> 6;
    float a2 = logits[tid], b2 = logits[tid + 256];
    float m = fmaxf(a2, b2);
    #pragma unroll
    for (int off = 32; off > 0; off >>= 1) m = fmaxf(m, __shfl_xor(m, off));
    if ((tid & 63) == 0) red[wave] = m;
    __syncthreads();
    m = fmaxf(fmaxf(red[0], red[1]), fmaxf(red[2], red[3]));
    __syncthreads();
    float e = __expf(a2 - m) + __expf(b2 - m);
    #pragma unroll
    for (int off = 32; off > 0; off >>= 1) e += __shfl_xor(e, off);
    if ((tid & 63) == 0) red[wave] = e;
    __syncthreads();
    if (tid == 0) {
        float tot = red[0] + red[1] + red[2] + red[3];
        float lse = m + logf(tot);
        float q0  = fmaxf(q[cidx[0]], 1e-10f);
        atomicAdd(out, (-logits[0] + lse + logf(q0)) * (1.0f / N_ROWS));
    }
}
#endif  // HAVE_PERM

// ======================= FP8 path (round-7, verified) =======================
#define SCALE     64.0f
#define INV_SCALE (1.0f / 64.0f)

__device__ __forceinline__ float dot16(uint4 wv, const float4* hh, float s) {
    v2f p;
    p = F8X2(wv.x, 0); s = fmaf(p.x, hh[0].x, s); s = fmaf(p.y, hh[0].y, s);
    p = F8X2(wv.x, 1); s = fmaf(p.x, hh[0].z, s); s = fmaf(p.y, hh[0].w, s);
    p = F8X2(wv.y, 0); s = fmaf(p.x, hh[1].x, s); s = fmaf(p.y, hh[1].y, s);
    p = F8X2(wv.y, 1); s = fmaf(p.x, hh[1].z, s); s = fmaf(p.y, hh[1].w, s);
    p = F8X2(wv.z, 0); s = fmaf(p.x, hh[2].x, s); s = fmaf(p.y, hh[2].y, s);
    p = F8X2(wv.z, 1); s = fmaf(p.x, hh[2].z, s); s = fmaf(p.y, hh[2].w, s);
    p = F8X2(wv.w, 0); s = fmaf(p.x, hh[3].x, s); s = fmaf(p.y, hh[3].y, s);
    p = F8X2(wv.w, 1); s = fmaf(p.x, hh[3].z, s); s = fmaf(p.y, hh[3].w, s);
    return s;
}

__global__ __launch_bounds__(256) void k_convert_fp8(const float* __restrict__ W,
                                                     uint2* __restrict__ Wf8,
                                                     float* __restrict__ out) {
    if (blockIdx.x == 0 && threadIdx.x == 0) out[0] = 0.0f;
    const size_t nvec = W_ELEMS / 8;
    const size_t stride = (size_t)gridDim.x * 256;
    for (size_t i = (size_t)blockIdx.x * 256 + threadIdx.x; i < nvec; i += stride) {
        float4 v0 = reinterpret_cast<const float4*>(W)[2 * i];
        float4 v1 = reinterpret_cast<const float4*>(W)[2 * i + 1];
        uint2 o;
        o.x = pack4(v0.x * SCALE, v0.y * SCALE, v0.z * SCALE, v0.w * SCALE);
        o.y = pack4(v1.x * SCALE, v1.y * SCALE, v1.z * SCALE, v1.w * SCALE);
        Wf8[i] = o;
    }
}

__global__ __launch_bounds__(256) void k_main_fp8(
    const float* __restrict__ H, const int* __restrict__ labels,
    const unsigned* __restrict__ Wf8, const float* __restrict__ q,
    const int* __restrict__ neg, float* __restrict__ out)
{
    const int n   = blockIdx.x;
    const int tid = threadIdx.x;
    const int sub = tid & 15;
    const int grp = tid >> 4;
    __shared__ int   cidx[K_SZ];
    __shared__ float logits[K_SZ];
    __shared__ float red[4];
    for (int i = tid; i < K_SZ; i += 256)
        cidx[i] = (i == 0) ? labels[n] : neg[(size_t)n * KM1 + (i - 1)];
    const float4* Hr4 = reinterpret_cast<const float4*>(H + (size_t)n * D_SZ);
    float4 ha[4], hb[4];
    #pragma unroll
    for (int j = 0; j < 4; ++j) {
        ha[j] = Hr4[sub * 4 + j];
        hb[j] = Hr4[64 + sub * 4 + j];
    }
    __syncthreads();
    for (int base = grp; base < K_SZ; base += 32) {
        const int c0 = cidx[base], c1 = cidx[base + 16];
        const uint4* Wr0 = reinterpret_cast<const uint4*>(Wf8 + (size_t)c0 * (D_SZ / 4));
        const uint4* Wr1 = reinterpret_cast<const uint4*>(Wf8 + (size_t)c1 * (D_SZ / 4));
        uint4 a0 = Wr0[sub], a1 = Wr0[16 + sub];
        uint4 b0 = Wr1[sub], b1 = Wr1[16 + sub];
        float s0 = dot16(a1, hb, dot16(a0, ha, 0.f));
        float s1 = dot16(b1, hb, dot16(b0, ha, 0.f));
        s0 += __shfl_xor(s0, 1); s1 += __shfl_xor(s1, 1);
        s0 += __shfl_xor(s0, 2); s1 += __shfl_xor(s1, 2);
        s0 += __shfl_xor(s0, 4); s1 += __shfl_xor(s1, 4);
        s0 += __shfl_xor(s0, 8); s1 += __shfl_xor(s1, 8);
        if (sub == 0) { logits[base] = s0 * INV_SCALE; logits[base + 16] = s1 * INV_SCALE; }
    }
    __syncthreads();
    const int wave = tid >> 6;
    float a = logits[tid], b2 = logits[tid + 256];
    float m = fmaxf(a, b2);
    #pragma unroll
    for (int off = 32; off > 0; off >>= 1) m = fmaxf(m, __shfl_xor(m, off));
    if ((tid & 63) == 0) red[wave] = m;
    __syncthreads();
    m = fmaxf(fmaxf(red[0], red[1]), fmaxf(red[2], red[3]));
    __syncthreads();
    float e = __expf(a - m) + __expf(b2 - m);
    #pragma unroll
    for (int off = 32; off > 0; off >>= 1) e += __shfl_xor(e, off);
    if ((tid & 63) == 0) red[wave] = e;
    __syncthreads();
    if (tid == 0) {
        float tot = red[0] + red[1] + red[2] + red[3];
        float lse = m + logf(tot);
        float q0  = fmaxf(q[cidx[0]], 1e-10f);
        atomicAdd(out, (-logits[0] + lse + logf(q0)) * (1.0f / N_ROWS));
    }
}

// ======================= FP32 last-resort fallback =======================
__global__ void zero_out_kernel(float* out) { out[0] = 0.0f; }

__global__ __launch_bounds__(256) void sampled_softmax_loss_kernel(
    const float* __restrict__ H, const int* __restrict__ labels,
    const float* __restrict__ W, const float* __restrict__ q,
    const int* __restrict__ neg, float* __restrict__ out)
{
    const int n = blockIdx.x, tid = threadIdx.x;
    const int sub = tid & 15, grp = tid >> 4;
    __shared__ int   cidx[K_SZ];
    __shared__ float logits[K_SZ];
    __shared__ float red[4];
    for (int i = tid; i < K_SZ; i += 256)
        cidx[i] = (i == 0) ? labels[n] : neg[(size_t)n * KM1 + (i - 1)];
    float4 h[8];
    const float4* Hrow = reinterpret_cast<const float4*>(H + (size_t)n * D_SZ);
    #pragma unroll
    for (int ch = 0; ch < 8; ++ch) h[ch] = Hrow[sub + ch * 16];
    __syncthreads();
    for (int base = grp; base < K_SZ; base += 16) {
        const float4* Wrow = reinterpret_cast<const float4*>(W + (size_t)cidx[base] * D_SZ);
        float4 acc = make_float4(0.f, 0.f, 0.f, 0.f);
        #pragma unroll
        for (int ch = 0; ch < 8; ++ch) {
            float4 w = Wrow[sub + ch * 16];
            acc.x = fmaf(w.x, h[ch].x, acc.x); acc.y = fmaf(w.y, h[ch].y, acc.y);
            acc.z = fmaf(w.z, h[ch].z, acc.z); acc.w = fmaf(w.w, h[ch].w, acc.w);
        }
        float s = (acc.x + acc.y) + (acc.z + acc.w);
        s += __shfl_xor(s, 1); s += __shfl_xor(s, 2);
        s += __shfl_xor(s, 4); s += __shfl_xor(s, 8);
        if (sub == 0) logits[base] = s;
    }
    __syncthreads();
    const int wave = tid >> 6;
    float m = -INFINITY;
    for (int i = tid; i < K_SZ; i += 256) m = fmaxf(m, logits[i]);
    #pragma unroll
    for (int off = 32; off > 0; off >>= 1) m = fmaxf(m, __shfl_xor(m, off));
    if ((tid & 63) == 0) red[wave] = m;
    __syncthreads();
    m = fmaxf(fmaxf(red[0], red[1]), fmaxf(red[2], red[3]));
    __syncthreads();
    float s = 0.f;
    for (int i = tid; i < K_SZ; i += 256) s += expf(logits[i] - m);
    #pragma unroll
    for (int off = 32; off > 0; off >>= 1) s += __shfl_xor(s, off);
    if ((tid & 63) == 0) red[wave] = s;
    __syncthreads();
    if (tid == 0) {
        float tot = red[0] + red[1] + red[2] + red[3];
        float lse = m + logf(tot);
        float q0 = fmaxf(q[cidx[0]], 1e-10f);
        atomicAdd(out, (-logits[0] + lse + logf(q0)) * (1.0f / N_ROWS));
    }
}

// ---------------- launch ----------------
extern "C" void kernel_launch(void* const* d_in, const int* in_sizes, int n_in,
                              void* d_out, int out_size, void* d_ws, size_t ws_size,
                              hipStream_t stream) {
    const float* H      = (const float*)d_in[0];
    const int*   labels = (const int*)  d_in[1];
    const float* W      = (const float*)d_in[2];
    const float* q      = (const float*)d_in[3];
    const int*   neg    = (const int*)  d_in[4];
    float* out = (float*)d_out;

#ifdef HAVE_PERM
    if (ws_size >= W_ELEMS / 2) {   // 32,768,000 B fp4 table
        unsigned* W4 = (unsigned*)d_ws;
        k_convert_fp4<<<2048, 256, 0, stream>>>(W, W4, out);
        k_main_fp4   <<<N_ROWS, 256, 0, stream>>>(H, labels, W4, q, neg, out);
        return;
    }
#endif
    if (ws_size >= W_ELEMS) {       // 65,536,000 B fp8 table
        unsigned* Wf8 = (unsigned*)d_ws;
        k_convert_fp8<<<2048, 256, 0, stream>>>(W, (uint2*)Wf8, out);
        k_main_fp8   <<<N_ROWS, 256, 0, stream>>>(H, labels, Wf8, q, neg, out);
    } else {
        zero_out_kernel<<<1, 1, 0, stream>>>(out);
        sampled_softmax_loss_kernel<<<N_ROWS, 256, 0, stream>>>(H, labels, W, q, neg, out);
    }
}